// Round 1
// baseline (236.907 us; speedup 1.0000x reference)
//
#include <hip/hip_runtime.h>

// HollywoodFFT: B=4096 rows of N=4096 complex FFT (split re/im fp32).
// Radix-16 x 3 passes, one workgroup (256 thr) per row.
// R3 changes vs R2:
//  - Global I/O is DIRECT (dword-coalesced 256B/wave): no stage-in/stage-out
//    LDS round trips. Pass A reads x[t+256c]; pass C NT-stores out[t+256w].
//  - LDS holds interleaved complex (float2, 32 KB): all LDS traffic is b64.
//    Per-thread LDS ops drop 224 (192 b32 + 16 b128 + 16 b128) -> 64 b64.
//  - Pass B is IN-PLACE: thread (a,u) owns slot set {a+16s+256u} exclusively
//    (reads and writes only its own slots), so no barrier between B-read and
//    B-write. Barriers per block: 5 -> 2.
// n = a + 16b + 256c ; k = u + 16v + 256w (digits in [0,16)):
//   S1[a][b][u] = DFT16_c x[a+16b+256c]
//   S2 = S1 * W256^{b u}          (applied on pass-B read)
//   S3[a][u][v] = DFT16_b S2
//   S4 = S3 * W4096^{a(u+16v)}    (applied on pass-C read)
//   X[u+16v+256w] = DFT16_a S4
// LDS layouts (complex-slot index in [0,4096)):
//   L1: slot(a,b,u) = a + 16*(b^u) + 256*u   (A-write / B-read)
//   L2: slot(a,u,v) = a + 16*v     + 256*u   (B-write in-place / C-read)
// Conflict-freedom (b64: need slot%16 distinct within each 16-lane group):
//   A-write: group has a=0..15, (b,u) fixed -> col = a      : distinct
//   B-read : group has a=0..15, (u,bb) fixed -> col = a     : distinct
//   B-write: group has a=0..15, (u,v) fixed -> col = a      : distinct
//   C-read : group has u2=0..15, v2 fixed; aa=(s+u2)&15 -> col varies : distinct

#define NFFT 4096

__device__ __forceinline__ void fft16(float xr[16], float xi[16]) {
    // natural-order in/out 16-point DFT: bit-rev permute + 4 radix-2 DIT stages
    const int br[16] = {0,8,4,12,2,10,6,14,1,9,5,13,3,11,7,15};
    float yr[16], yi[16];
#pragma unroll
    for (int j = 0; j < 16; ++j) { yr[j] = xr[br[j]]; yi[j] = xi[br[j]]; }
    const float W16r[8] = { 1.0f,  0.92387953251128675613f,  0.70710678118654752440f,
                            0.38268343236508977173f,  0.0f, -0.38268343236508977173f,
                           -0.70710678118654752440f, -0.92387953251128675613f };
    const float W16i[8] = { 0.0f, -0.38268343236508977173f, -0.70710678118654752440f,
                           -0.92387953251128675613f, -1.0f, -0.92387953251128675613f,
                           -0.70710678118654752440f, -0.38268343236508977173f };
#pragma unroll
    for (int s = 0; s < 4; ++s) {
        const int stride = 1 << s;
        const int tm = 8 >> s;
#pragma unroll
        for (int g = 0; g < 16; g += 2 * stride) {
#pragma unroll
            for (int p = 0; p < stride; ++p) {
                const int i0 = g + p, i1 = i0 + stride;
                const float twr = W16r[p * tm], twi = W16i[p * tm];
                const float brr = yr[i1] * twr - yi[i1] * twi;
                const float bii = yr[i1] * twi + yi[i1] * twr;
                const float ar = yr[i0], ai = yi[i0];
                yr[i0] = ar + brr; yi[i0] = ai + bii;
                yr[i1] = ar - brr; yi[i1] = ai - bii;
            }
        }
    }
#pragma unroll
    for (int j = 0; j < 16; ++j) { xr[j] = yr[j]; xi[j] = yi[j]; }
}

__global__ __launch_bounds__(256, 5)
void HollywoodFFT_53584011985637_kernel(const float* __restrict__ xre,
                                        const float* __restrict__ xim,
                                        float* __restrict__ outre,
                                        float* __restrict__ outim) {
    __shared__ __align__(16) float2 l[NFFT];   // 32 KB -> 5 blocks/CU

    const int t = threadIdx.x;
    const long long row = blockIdx.x;
    const float* __restrict__ xr_row = xre + row * NFFT;
    const float* __restrict__ xi_row = xim + row * NFFT;

    float vr[16], vi[16];
    const int a = t & 15;   // low digit of thread id
    const int h = t >> 4;   // high digit: plays b in pass A, u in pass B

    // ---- Pass A: direct global read n = t + 256c (dword-coalesced), DFT16 over c
#pragma unroll
    for (int c = 0; c < 16; ++c) {
        vr[c] = xr_row[t + 256 * c];
        vi[c] = xi_row[t + 256 * c];
    }
    fft16(vr, vi);
#pragma unroll
    for (int uu = 0; uu < 16; ++uu) {   // L1: a + 16*(b^u) + 256*u  (b = h)
        l[a + 16 * (h ^ uu) + 256 * uu] = make_float2(vr[uu], vi[uu]);
    }
    __syncthreads();

    // ---- Pass B: thread (a, u=h). Read over b w/ twiddle W256^{bu}, DFT16 over b
    {
        float s0, c0;
        __sincosf(-6.28318530717958647692f * (float)h * (1.0f / 256.0f), &s0, &c0);
        float twr = 1.0f, twi = 0.0f;
#pragma unroll
        for (int bb = 0; bb < 16; ++bb) {
            const float2 xv = l[a + 16 * (bb ^ h) + 256 * h];
            vr[bb] = xv.x * twr - xv.y * twi;
            vi[bb] = xv.x * twi + xv.y * twr;
            const float ntr = twr * c0 - twi * s0;
            twi = twr * s0 + twi * c0;
            twr = ntr;
        }
    }
    fft16(vr, vi);
    // In-place write back into this thread's private slot set (no barrier needed):
#pragma unroll
    for (int v = 0; v < 16; ++v) {      // L2: a + 16*v + 256*u
        l[a + 16 * v + 256 * h] = make_float2(vr[v], vi[v]);
    }
    __syncthreads();

    // ---- Pass C: thread (u2=t&15, v2=t>>4). Rotated-order read aa=(s+u2)&15
    //      with twiddle W4096^{aa*(u2+16v2)}; DFT16 over a; direct NT store.
    const int u2 = a, v2 = h;
    {
        const int K = u2 + 16 * v2;                    // == t
        float sW, cW;                                  // W = W4096^K
        __sincosf(-6.28318530717958647692f * (float)K * (1.0f / 4096.0f), &sW, &cW);
        const int m0 = (u2 * K) & 4095;                // exact mod for start angle
        float twr, twi;                                // tw = W4096^{u2*K}
        __sincosf(-6.28318530717958647692f * (float)m0 * (1.0f / 4096.0f), &twi, &twr);
#pragma unroll
        for (int s = 0; s < 16; ++s) {
            const int aa = (s + u2) & 15;
            const float2 xv = l[aa + 16 * v2 + 256 * u2];
            vr[aa] = xv.x * twr - xv.y * twi;
            vi[aa] = xv.x * twi + xv.y * twr;
            // advance tw *= W; reset to 1 at the wrap (next aa == 0)
            const float ntr = twr * cW - twi * sW;
            const float nti = twr * sW + twi * cW;
            twr = (aa == 15) ? 1.0f : ntr;
            twi = (aa == 15) ? 0.0f : nti;
        }
    }
    fft16(vr, vi);

    float* __restrict__ or_row = outre + row * NFFT;
    float* __restrict__ oi_row = outim + row * NFFT;
#pragma unroll
    for (int w = 0; w < 16; ++w) {      // k = u2 + 16*v2 + 256*w = t + 256*w
        __builtin_nontemporal_store(vr[w], or_row + t + 256 * w);
        __builtin_nontemporal_store(vi[w], oi_row + t + 256 * w);
    }
}

extern "C" void kernel_launch(void* const* d_in, const int* in_sizes, int n_in,
                              void* d_out, int out_size, void* d_ws, size_t ws_size,
                              hipStream_t stream) {
    const float* xre = (const float*)d_in[0];
    const float* xim = (const float*)d_in[1];
    const int B = in_sizes[0] / NFFT;            // 4096 rows
    float* out = (float*)d_out;
    float* outre = out;
    float* outim = out + (size_t)B * NFFT;       // outputs concatenated flat
    HollywoodFFT_53584011985637_kernel<<<dim3(B), dim3(256), 0, stream>>>(
        xre, xim, outre, outim);
}

// Round 2
// 235.776 us; speedup vs baseline: 1.0048x; 1.0048x over previous
//
#include <hip/hip_runtime.h>

// HollywoodFFT: B=4096 rows of N=4096 complex FFT (split re/im fp32).
// Radix-16 x 3 passes, one workgroup (256 thr) per row.
// R4 = R3 structure with the register-indexing poison removed:
//  - Global I/O DIRECT (dword-coalesced 256B/wave): pass A reads x[t+256c],
//    pass C NT-stores out[t+256w]. No stage-in/out LDS round trips.
//  - LDS holds interleaved complex (float2, 32 KB): all LDS traffic is b64.
//  - ALL register-array indices are compile-time loop constants (R3's pass C
//    used vr[(s+u2)&15] -- per-lane runtime index -> compiler emitted 16-way
//    cmp+cndmask chains, doubling VALUBusy. Reverted to static order.)
//  - Pass B is no longer in-place; L2 uses the R2-proven XOR layout instead,
//    which keeps pass C conflict-free WITH static register order.
//    Barriers per block: 3 (R2 had 7, R3 had 2).
// n = a + 16b + 256c ; k = u + 16v + 256w (digits in [0,16)):
//   S1[a][b][u] = DFT16_c x[a+16b+256c]
//   S2 = S1 * W256^{b u}          (applied on pass-B read)
//   S3[a][u][v] = DFT16_b S2
//   S4 = S3 * W4096^{a(u+16v)}    (applied on pass-C read)
//   X[u+16v+256w] = DFT16_a S4
// LDS layouts (complex-slot index in [0,4096)):
//   L1: slot(a,b,u) = a     + 16*(b^u) + 256*u   (A-write / B-read)
//   L2: slot(a,u,v) = (a^u) + 16*(u^v) + 256*v   (B-write / C-read)
// Conflict-freedom (slot%16 distinct within each 16-lane group):
//   A-write: lanes a=0..15, (b,u) fixed -> col = a        : distinct
//   B-read : lanes a=0..15, (u,bb) fixed -> col = a       : distinct
//   B-write: lanes a=0..15, (u,v) fixed -> col = a^u      : distinct
//   C-read : lanes u2=0..15, (v2,aa) fixed -> col = aa^u2 : distinct

#define NFFT 4096

__device__ __forceinline__ void fft16(float xr[16], float xi[16]) {
    // natural-order in/out 16-point DFT: bit-rev permute + 4 radix-2 DIT stages
    const int br[16] = {0,8,4,12,2,10,6,14,1,9,5,13,3,11,7,15};
    float yr[16], yi[16];
#pragma unroll
    for (int j = 0; j < 16; ++j) { yr[j] = xr[br[j]]; yi[j] = xi[br[j]]; }
    const float W16r[8] = { 1.0f,  0.92387953251128675613f,  0.70710678118654752440f,
                            0.38268343236508977173f,  0.0f, -0.38268343236508977173f,
                           -0.70710678118654752440f, -0.92387953251128675613f };
    const float W16i[8] = { 0.0f, -0.38268343236508977173f, -0.70710678118654752440f,
                           -0.92387953251128675613f, -1.0f, -0.92387953251128675613f,
                           -0.70710678118654752440f, -0.38268343236508977173f };
#pragma unroll
    for (int s = 0; s < 4; ++s) {
        const int stride = 1 << s;
        const int tm = 8 >> s;
#pragma unroll
        for (int g = 0; g < 16; g += 2 * stride) {
#pragma unroll
            for (int p = 0; p < stride; ++p) {
                const int i0 = g + p, i1 = i0 + stride;
                const float twr = W16r[p * tm], twi = W16i[p * tm];
                const float brr = yr[i1] * twr - yi[i1] * twi;
                const float bii = yr[i1] * twi + yi[i1] * twr;
                const float ar = yr[i0], ai = yi[i0];
                yr[i0] = ar + brr; yi[i0] = ai + bii;
                yr[i1] = ar - brr; yi[i1] = ai - bii;
            }
        }
    }
#pragma unroll
    for (int j = 0; j < 16; ++j) { xr[j] = yr[j]; xi[j] = yi[j]; }
}

__global__ __launch_bounds__(256, 5)
void HollywoodFFT_53584011985637_kernel(const float* __restrict__ xre,
                                        const float* __restrict__ xim,
                                        float* __restrict__ outre,
                                        float* __restrict__ outim) {
    __shared__ __align__(16) float2 l[NFFT];   // 32 KB -> 5 blocks/CU

    const int t = threadIdx.x;
    const long long row = blockIdx.x;
    const float* __restrict__ xr_row = xre + row * NFFT;
    const float* __restrict__ xi_row = xim + row * NFFT;

    float vr[16], vi[16];
    const int a = t & 15;   // low digit of thread id
    const int h = t >> 4;   // high digit: plays b in pass A, u in pass B

    // ---- Pass A: direct global read n = t + 256c (dword-coalesced), DFT16 over c
#pragma unroll
    for (int c = 0; c < 16; ++c) {
        vr[c] = xr_row[t + 256 * c];
        vi[c] = xi_row[t + 256 * c];
    }
    fft16(vr, vi);
#pragma unroll
    for (int uu = 0; uu < 16; ++uu) {   // L1: a + 16*(b^u) + 256*u  (b = h)
        l[a + 16 * (h ^ uu) + 256 * uu] = make_float2(vr[uu], vi[uu]);
    }
    __syncthreads();

    // ---- Pass B: thread (a, u=h). Read over b w/ twiddle W256^{bu}, DFT16 over b
    {
        float s0, c0;
        __sincosf(-6.28318530717958647692f * (float)h * (1.0f / 256.0f), &s0, &c0);
        float twr = 1.0f, twi = 0.0f;
#pragma unroll
        for (int bb = 0; bb < 16; ++bb) {
            const float2 xv = l[a + 16 * (bb ^ h) + 256 * h];
            vr[bb] = xv.x * twr - xv.y * twi;
            vi[bb] = xv.x * twi + xv.y * twr;
            const float ntr = twr * c0 - twi * s0;
            twi = twr * s0 + twi * c0;
            twr = ntr;
        }
    }
    fft16(vr, vi);
    __syncthreads();                 // all L1 reads done before L2 writes
#pragma unroll
    for (int v = 0; v < 16; ++v) {   // L2: (a^u) + 16*(u^v) + 256*v
        l[(a ^ h) + 16 * (h ^ v) + 256 * v] = make_float2(vr[v], vi[v]);
    }
    __syncthreads();

    // ---- Pass C: thread (u2=t&15, v2=t>>4). Static-order read over aa with
    //      twiddle W4096^{aa*(u2+16v2)}; DFT16 over a; direct NT store.
    const int u2 = a, v2 = h;
    {
        float s0, c0;                                  // W = W4096^{u2+16v2}
        __sincosf(-6.28318530717958647692f * (float)(u2 + 16 * v2) * (1.0f / 4096.0f),
                  &s0, &c0);
        float twr = 1.0f, twi = 0.0f;
#pragma unroll
        for (int aa = 0; aa < 16; ++aa) {
            const float2 xv = l[(aa ^ u2) + 16 * (u2 ^ v2) + 256 * v2];
            vr[aa] = xv.x * twr - xv.y * twi;
            vi[aa] = xv.x * twi + xv.y * twr;
            const float ntr = twr * c0 - twi * s0;
            twi = twr * s0 + twi * c0;
            twr = ntr;
        }
    }
    fft16(vr, vi);

    float* __restrict__ or_row = outre + row * NFFT;
    float* __restrict__ oi_row = outim + row * NFFT;
#pragma unroll
    for (int w = 0; w < 16; ++w) {      // k = u2 + 16*v2 + 256*w = t + 256*w
        __builtin_nontemporal_store(vr[w], or_row + t + 256 * w);
        __builtin_nontemporal_store(vi[w], oi_row + t + 256 * w);
    }
}

extern "C" void kernel_launch(void* const* d_in, const int* in_sizes, int n_in,
                              void* d_out, int out_size, void* d_ws, size_t ws_size,
                              hipStream_t stream) {
    const float* xre = (const float*)d_in[0];
    const float* xim = (const float*)d_in[1];
    const int B = in_sizes[0] / NFFT;            // 4096 rows
    float* out = (float*)d_out;
    float* outre = out;
    float* outim = out + (size_t)B * NFFT;       // outputs concatenated flat
    HollywoodFFT_53584011985637_kernel<<<dim3(B), dim3(256), 0, stream>>>(
        xre, xim, outre, outim);
}